// Round 1
// baseline (3462.851 us; speedup 1.0000x reference)
//
#include <hip/hip_runtime.h>

#define B_  4
#define S_  2048
#define D_  1024
#define H_  16
#define DH_ 64
#define M_  (B_*S_)   // 8192

// ================= GEMM: Y = (X @ W + bias) * scale =================
// X: (M,K) row-major; W: (K,N) row-major (in,out); bias: (N)
// headed==1: Y laid out (B,H,S,DH); headed==0: Y laid out (M,N)
constexpr int BM = 128, BN = 128, BK = 16;

__global__ __launch_bounds__(256, 2) void gemm_bias(
    const float* __restrict__ X, const float* __restrict__ W,
    const float* __restrict__ bias, float* __restrict__ Y,
    int K, int N, float scale, int headed)
{
    __shared__ float As[BK][BM + 4];   // stride 132, transposed A tile
    __shared__ float Bs[BK][BN + 4];   // stride 132

    const int tid = threadIdx.x;
    const int m0 = blockIdx.y * BM;
    const int n0 = blockIdx.x * BN;
    const int tx = tid & 15, ty = tid >> 4;

    float acc[8][8] = {};

    const int ar = tid >> 1, ac = (tid & 1) * 8;   // A tile: 128 rows x 16 k
    const int br = tid >> 4, bc = (tid & 15) * 8;  // B tile: 16 k x 128 n

    for (int k0 = 0; k0 < K; k0 += BK) {
        __syncthreads();
        float4 a0 = *reinterpret_cast<const float4*>(&X[(size_t)(m0 + ar) * K + k0 + ac]);
        float4 a1 = *reinterpret_cast<const float4*>(&X[(size_t)(m0 + ar) * K + k0 + ac + 4]);
        As[ac + 0][ar] = a0.x; As[ac + 1][ar] = a0.y; As[ac + 2][ar] = a0.z; As[ac + 3][ar] = a0.w;
        As[ac + 4][ar] = a1.x; As[ac + 5][ar] = a1.y; As[ac + 6][ar] = a1.z; As[ac + 7][ar] = a1.w;
        *reinterpret_cast<float4*>(&Bs[br][bc]) =
            *reinterpret_cast<const float4*>(&W[(size_t)(k0 + br) * N + n0 + bc]);
        *reinterpret_cast<float4*>(&Bs[br][bc + 4]) =
            *reinterpret_cast<const float4*>(&W[(size_t)(k0 + br) * N + n0 + bc + 4]);
        __syncthreads();

        #pragma unroll
        for (int kk = 0; kk < BK; ++kk) {
            float a[8], b[8];
            *reinterpret_cast<float4*>(&a[0]) = *reinterpret_cast<const float4*>(&As[kk][ty * 8]);
            *reinterpret_cast<float4*>(&a[4]) = *reinterpret_cast<const float4*>(&As[kk][ty * 8 + 4]);
            *reinterpret_cast<float4*>(&b[0]) = *reinterpret_cast<const float4*>(&Bs[kk][tx * 8]);
            *reinterpret_cast<float4*>(&b[4]) = *reinterpret_cast<const float4*>(&Bs[kk][tx * 8 + 4]);
            #pragma unroll
            for (int i = 0; i < 8; ++i)
                #pragma unroll
                for (int j = 0; j < 8; ++j)
                    acc[i][j] = fmaf(a[i], b[j], acc[i][j]);
        }
    }

    #pragma unroll
    for (int i = 0; i < 8; ++i) {
        int m = m0 + ty * 8 + i;
        int b = m >> 11;            // m / S_
        int s = m & (S_ - 1);
        #pragma unroll
        for (int j4 = 0; j4 < 2; ++j4) {
            int n = n0 + tx * 8 + j4 * 4;
            float4 o;
            o.x = (acc[i][j4 * 4 + 0] + bias[n + 0]) * scale;
            o.y = (acc[i][j4 * 4 + 1] + bias[n + 1]) * scale;
            o.z = (acc[i][j4 * 4 + 2] + bias[n + 2]) * scale;
            o.w = (acc[i][j4 * 4 + 3] + bias[n + 3]) * scale;
            if (headed) {
                int h = n >> 6, dh = n & 63;
                *reinterpret_cast<float4*>(&Y[((((size_t)b * H_ + h) * S_ + s) << 6) + dh]) = o;
            } else {
                *reinterpret_cast<float4*>(&Y[(size_t)m * N + n]) = o;
            }
        }
    }
}

// ================= Flash attention (fp32, online softmax) =================
// q,k,v: (B,H,S,DH) head-major; mask: (B,S) additive; ctx: (B,S,D)
__global__ __launch_bounds__(256, 2) void flash_attn(
    const float* __restrict__ q, const float* __restrict__ k,
    const float* __restrict__ v, const float* __restrict__ mask,
    float* __restrict__ ctx)
{
    __shared__ float Ks[64][68];
    __shared__ float Vs[64][68];
    __shared__ float Ps[64][68];

    const int tid = threadIdx.x;
    const int bh  = blockIdx.y;       // b*H + h
    const int bb  = bh >> 4;          // / H_
    const int hh  = bh & 15;
    const int q0  = blockIdx.x * 64;
    const int row = tid >> 2;         // q-row within tile (0..63)
    const int sub = tid & 3;          // quad member: owns 16 k-cols / 16 out-dims

    const float* qp = q + (size_t)bh * (S_ * 64);
    const float* kp = k + (size_t)bh * (S_ * 64);
    const float* vp = v + (size_t)bh * (S_ * 64);
    const float* mp = mask + (size_t)bb * S_;

    float qreg[64];
    {
        const float* qr = qp + (size_t)(q0 + row) * 64;
        #pragma unroll
        for (int i = 0; i < 16; ++i)
            *reinterpret_cast<float4*>(&qreg[i * 4]) =
                *reinterpret_cast<const float4*>(&qr[i * 4]);
    }

    float o[16];
    #pragma unroll
    for (int i = 0; i < 16; ++i) o[i] = 0.f;
    float mrun = -1e30f, lrun = 0.f;

    const int lr = tid >> 2, lc = (tid & 3) * 16;  // K/V tile loader indices

    for (int kt = 0; kt < S_; kt += 64) {
        __syncthreads();   // prev iter's Vs/Ps reads done
        #pragma unroll
        for (int i = 0; i < 4; ++i) {
            *reinterpret_cast<float4*>(&Ks[lr][lc + i * 4]) =
                *reinterpret_cast<const float4*>(&kp[(size_t)(kt + lr) * 64 + lc + i * 4]);
            *reinterpret_cast<float4*>(&Vs[lr][lc + i * 4]) =
                *reinterpret_cast<const float4*>(&vp[(size_t)(kt + lr) * 64 + lc + i * 4]);
        }
        __syncthreads();

        // ---- scores for 16 k-cols: S[row][j] = q_row . k_j + mask[j] ----
        float p[16];
        float tmax = -1e30f;
        #pragma unroll
        for (int jj = 0; jj < 16; ++jj) {
            int j = sub * 16 + jj;
            float s_ = 0.f;
            #pragma unroll
            for (int d4 = 0; d4 < 16; ++d4) {
                float4 kv = *reinterpret_cast<const float4*>(&Ks[j][d4 * 4]);
                s_ = fmaf(qreg[d4 * 4 + 0], kv.x, s_);
                s_ = fmaf(qreg[d4 * 4 + 1], kv.y, s_);
                s_ = fmaf(qreg[d4 * 4 + 2], kv.z, s_);
                s_ = fmaf(qreg[d4 * 4 + 3], kv.w, s_);
            }
            s_ += mp[kt + j];
            p[jj] = s_;
            tmax = fmaxf(tmax, s_);
        }
        // quad (4 lanes per row) reductions
        tmax = fmaxf(tmax, __shfl_xor(tmax, 1));
        tmax = fmaxf(tmax, __shfl_xor(tmax, 2));
        float mnew  = fmaxf(mrun, tmax);
        float alpha = __expf(mrun - mnew);
        float lsum = 0.f;
        #pragma unroll
        for (int jj = 0; jj < 16; ++jj) {
            p[jj] = __expf(p[jj] - mnew);
            lsum += p[jj];
        }
        lsum += __shfl_xor(lsum, 1);
        lsum += __shfl_xor(lsum, 2);
        lrun = lrun * alpha + lsum;
        mrun = mnew;
        #pragma unroll
        for (int i = 0; i < 16; ++i) o[i] *= alpha;

        #pragma unroll
        for (int jj = 0; jj < 4; ++jj)
            *reinterpret_cast<float4*>(&Ps[row][sub * 16 + jj * 4]) =
                *reinterpret_cast<float4*>(&p[jj * 4]);
        __syncthreads();

        // ---- PV: o[dd] += sum_j P[row][j] * V[j][sub*16+dd] ----
        #pragma unroll
        for (int j4 = 0; j4 < 16; ++j4) {
            float4 pv = *reinterpret_cast<const float4*>(&Ps[row][j4 * 4]);
            float pj[4] = {pv.x, pv.y, pv.z, pv.w};
            #pragma unroll
            for (int jq = 0; jq < 4; ++jq) {
                int j = j4 * 4 + jq;
                #pragma unroll
                for (int d4 = 0; d4 < 4; ++d4) {
                    float4 vv = *reinterpret_cast<const float4*>(&Vs[j][sub * 16 + d4 * 4]);
                    o[d4 * 4 + 0] = fmaf(pj[jq], vv.x, o[d4 * 4 + 0]);
                    o[d4 * 4 + 1] = fmaf(pj[jq], vv.y, o[d4 * 4 + 1]);
                    o[d4 * 4 + 2] = fmaf(pj[jq], vv.z, o[d4 * 4 + 2]);
                    o[d4 * 4 + 3] = fmaf(pj[jq], vv.w, o[d4 * 4 + 3]);
                }
            }
        }
    }

    // ---- epilogue: ctx[(b, s, h*64 + sub*16 .. +15)] = o / l ----
    float inv = 1.f / lrun;
    int s = q0 + row;
    float* op = ctx + ((size_t)bb * S_ + s) * D_ + hh * 64 + sub * 16;
    #pragma unroll
    for (int i = 0; i < 4; ++i) {
        float4 ov;
        ov.x = o[i * 4 + 0] * inv;
        ov.y = o[i * 4 + 1] * inv;
        ov.z = o[i * 4 + 2] * inv;
        ov.w = o[i * 4 + 3] * inv;
        *reinterpret_cast<float4*>(&op[i * 4]) = ov;
    }
}

// ================= launch =================
extern "C" void kernel_launch(void* const* d_in, const int* in_sizes, int n_in,
                              void* d_out, int out_size, void* d_ws, size_t ws_size,
                              hipStream_t stream) {
    const float* query = (const float*)d_in[0];
    const float* key_  = (const float*)d_in[1];
    const float* value = (const float*)d_in[2];
    const float* mask  = (const float*)d_in[3];
    const float* Wq = (const float*)d_in[4];
    const float* bq = (const float*)d_in[5];
    const float* Wk = (const float*)d_in[6];
    const float* bk = (const float*)d_in[7];
    const float* Wv = (const float*)d_in[8];
    const float* bv = (const float*)d_in[9];
    const float* Wo = (const float*)d_in[10];
    const float* bo = (const float*)d_in[11];
    float* out = (float*)d_out;

    const size_t qkv = (size_t)B_ * H_ * S_ * DH_;   // 8,388,608 floats
    float* qws = (float*)d_ws;
    float* kws = qws + qkv;
    float* vws = kws + qkv;
    float* cws = vws + qkv;   // context (B,S,D)

    dim3 gb(D_ / BN, M_ / BM);   // (8, 64)
    gemm_bias<<<gb, 256, 0, stream>>>(query, Wq, bq, qws, D_, D_, 0.125f, 1);
    gemm_bias<<<gb, 256, 0, stream>>>(key_,  Wk, bk, kws, D_, D_, 1.0f,   1);
    gemm_bias<<<gb, 256, 0, stream>>>(value, Wv, bv, vws, D_, D_, 1.0f,   1);

    flash_attn<<<dim3(S_ / 64, B_ * H_), 256, 0, stream>>>(qws, kws, vws, mask, cws);

    gemm_bias<<<gb, 256, 0, stream>>>(cws, Wo, bo, out, D_, D_, 1.0f, 0);
}

// Round 2
// 402.968 us; speedup vs baseline: 8.5934x; 8.5934x over previous
//
#include <hip/hip_runtime.h>
#include <hip/hip_bf16.h>

#define B_  4
#define S_  2048
#define D_  1024
#define H_  16
#define DH_ 64
#define M_  (B_*S_)   // 8192

typedef __attribute__((ext_vector_type(8))) short bf16x8;   // 8 bf16 = 4 VGPRs
typedef __attribute__((ext_vector_type(4))) float f32x4;

// XOR-swizzle: spreads 16-byte slots of a 128-byte LDS row across banks.
// byte = row*128 + (colByte with its 16B-slot XORed by row&7)
static __device__ __forceinline__ int swzb(int row, int colByte) {
    return row * 128 + (((colByte & ~15) ^ ((row & 7) << 4)) | (colByte & 15));
}

// ---------------- weight transpose + bf16 convert: Wt[n][k] = bf16(W[k][n]) ----------------
__global__ __launch_bounds__(256) void wtrans(const float* __restrict__ W,
                                              __hip_bfloat16* __restrict__ Wt) {
    __shared__ float t[32][33];
    const int bx = blockIdx.x * 32;   // n block
    const int by = blockIdx.y * 32;   // k block
    const int tx = threadIdx.x, ty = threadIdx.y;   // (32, 8)
    #pragma unroll
    for (int i = 0; i < 32; i += 8)
        t[ty + i][tx] = W[(size_t)(by + ty + i) * D_ + bx + tx];   // t[k'][n']
    __syncthreads();
    #pragma unroll
    for (int i = 0; i < 32; i += 8)
        Wt[(size_t)(bx + ty + i) * D_ + by + tx] = __float2bfloat16(t[tx][ty + i]);
}

// ---------------- MFMA GEMM: Y = (X @ W + bias) * scale ----------------
// X: (8192, 1024); Wt: (1024 n, 1024 k) bf16 (= W transposed)
// MODE 0: X fp32 -> bf16 headed (B,H,S,DH)      (q, k; scale for q)
// MODE 2: X fp32 -> bf16 transposed (B,H,DH,S)  (v)
// MODE 3: X bf16 (ctx) -> fp32 flat (M,N)       (final)
template<int MODE>
__global__ __launch_bounds__(256, 2) void gemm_mfma(
    const void* __restrict__ Xv, const __hip_bfloat16* __restrict__ Wt,
    const float* __restrict__ bias, void* __restrict__ Yv, float scale)
{
    __shared__ char Abuf[128 * 128];   // 128 rows x 64 bf16 (swizzled)
    __shared__ char Bbuf[128 * 128];

    const int tid = threadIdx.x;
    const int m0 = blockIdx.y * 128;
    const int n0 = blockIdx.x * 128;
    const int w  = tid >> 6, l = tid & 63;
    const int wm = w >> 1,  wn = w & 1;
    const int li = l & 15,  lg = l >> 4;

    f32x4 acc[4][4];
    #pragma unroll
    for (int a = 0; a < 4; ++a)
        #pragma unroll
        for (int b = 0; b < 4; ++b)
            acc[a][b] = (f32x4){0.f, 0.f, 0.f, 0.f};

    for (int k0 = 0; k0 < D_; k0 += 64) {
        // ---- stage A (convert fp32->bf16 unless MODE 3) ----
        #pragma unroll
        for (int c = 0; c < 4; ++c) {
            int chunk = tid * 4 + c;            // 1024 chunks of 8 bf16
            int row = chunk >> 3, colc = chunk & 7;
            if (MODE == 3) {
                const __hip_bfloat16* src = (const __hip_bfloat16*)Xv
                    + (size_t)(m0 + row) * D_ + k0 + colc * 8;
                *(bf16x8*)(Abuf + swzb(row, colc * 16)) = *(const bf16x8*)src;
            } else {
                const float* src = (const float*)Xv + (size_t)(m0 + row) * D_ + k0 + colc * 8;
                float4 x0 = *(const float4*)src;
                float4 x1 = *(const float4*)(src + 4);
                __hip_bfloat16 h[8];
                h[0] = __float2bfloat16(x0.x); h[1] = __float2bfloat16(x0.y);
                h[2] = __float2bfloat16(x0.z); h[3] = __float2bfloat16(x0.w);
                h[4] = __float2bfloat16(x1.x); h[5] = __float2bfloat16(x1.y);
                h[6] = __float2bfloat16(x1.z); h[7] = __float2bfloat16(x1.w);
                *(bf16x8*)(Abuf + swzb(row, colc * 16)) = *(const bf16x8*)h;
            }
            // ---- stage B (Wt already bf16) ----
            const __hip_bfloat16* bsrc = Wt + (size_t)(n0 + row) * D_ + k0 + colc * 8;
            *(bf16x8*)(Bbuf + swzb(row, colc * 16)) = *(const bf16x8*)bsrc;
        }
        __syncthreads();

        #pragma unroll
        for (int kh = 0; kh < 2; ++kh) {
            bf16x8 af[4], bf[4];
            #pragma unroll
            for (int mt = 0; mt < 4; ++mt)
                af[mt] = *(const bf16x8*)(Abuf + swzb(wm * 64 + mt * 16 + li, kh * 64 + lg * 16));
            #pragma unroll
            for (int nt = 0; nt < 4; ++nt)
                bf[nt] = *(const bf16x8*)(Bbuf + swzb(wn * 64 + nt * 16 + li, kh * 64 + lg * 16));
            #pragma unroll
            for (int mt = 0; mt < 4; ++mt)
                #pragma unroll
                for (int nt = 0; nt < 4; ++nt)
                    acc[mt][nt] = __builtin_amdgcn_mfma_f32_16x16x32_bf16(
                        af[mt], bf[nt], acc[mt][nt], 0, 0, 0);
        }
        __syncthreads();
    }

    // ---- epilogue ----
    #pragma unroll
    for (int mt = 0; mt < 4; ++mt) {
        #pragma unroll
        for (int nt = 0; nt < 4; ++nt) {
            int col = n0 + wn * 64 + nt * 16 + li;
            float bv = bias[col];
            #pragma unroll
            for (int i = 0; i < 4; ++i) {
                int row = m0 + wm * 64 + mt * 16 + lg * 4 + i;
                float v = (acc[mt][nt][i] + bv) * scale;
                if (MODE == 0) {
                    int b = row >> 11, s = row & (S_ - 1);
                    int h = col >> 6,  dh = col & 63;
                    ((__hip_bfloat16*)Yv)[((((size_t)b * H_ + h) * S_ + s) << 6) + dh] =
                        __float2bfloat16(v);
                } else if (MODE == 2) {
                    int b = row >> 11, s = row & (S_ - 1);
                    int h = col >> 6,  dh = col & 63;
                    ((__hip_bfloat16*)Yv)[((((size_t)b * H_ + h) * DH_ + dh) << 11) + s] =
                        __float2bfloat16(v);
                } else {
                    ((float*)Yv)[(size_t)row * D_ + col] = v;
                }
            }
        }
    }
}

// ---------------- MFMA flash attention ----------------
// q,k: (B,H,S,DH) bf16; vt: (B,H,DH,S) bf16; mask: (B,S) fp32; ctx: (B,S,D) bf16
__global__ __launch_bounds__(256, 2) void attn_mfma(
    const __hip_bfloat16* __restrict__ q, const __hip_bfloat16* __restrict__ k,
    const __hip_bfloat16* __restrict__ vt, const float* __restrict__ mask,
    __hip_bfloat16* __restrict__ ctx)
{
    __shared__ char Kb[64 * 128];      // K tile: [kv 64][dh 64] bf16, swizzled
    __shared__ char Vb[64 * 128];      // V^T tile: [dh 64][kv 64] bf16, swizzled
    __shared__ char Pb[64 * 128];      // P tile: [qrow 64][kv 64] bf16, swizzled
    __shared__ float mlds[S_];         // mask row (8 KB)

    const int tid = threadIdx.x;
    const int w  = tid >> 6, l = tid & 63;
    const int li = l & 15,  lg = l >> 4;
    const int bh = blockIdx.y;
    const int bb = bh >> 4, hh = bh & 15;
    const int q0 = blockIdx.x * 64;

    const __hip_bfloat16* qp = q  + (size_t)bh * (S_ * DH_);
    const __hip_bfloat16* kp = k  + (size_t)bh * (S_ * DH_);
    const __hip_bfloat16* vp = vt + (size_t)bh * (DH_ * S_);

    // mask row -> LDS
    {
        const float4* msrc = (const float4*)(mask + (size_t)bb * S_);
        for (int i = tid; i < S_ / 4; i += 256) ((float4*)mlds)[i] = msrc[i];
    }

    // Q fragments (wave's 16 rows, held in registers)
    bf16x8 qf[2];
    #pragma unroll
    for (int kh = 0; kh < 2; ++kh)
        qf[kh] = *(const bf16x8*)(qp + (size_t)(q0 + w * 16 + li) * DH_ + kh * 32 + lg * 8);

    f32x4 o[4];
    #pragma unroll
    for (int dt = 0; dt < 4; ++dt) o[dt] = (f32x4){0.f, 0.f, 0.f, 0.f};
    float mrow[4], lsum[4];
    #pragma unroll
    for (int i = 0; i < 4; ++i) { mrow[i] = -1e30f; lsum[i] = 0.f; }

    __syncthreads();   // mask ready

    for (int kt = 0; kt < S_; kt += 64) {
        // ---- stage K tile and V^T tile ----
        #pragma unroll
        for (int c = 0; c < 2; ++c) {
            int chunk = tid * 2 + c;            // 512 chunks of 8 bf16
            int row = chunk >> 3, colc = chunk & 7;
            *(bf16x8*)(Kb + swzb(row, colc * 16)) =
                *(const bf16x8*)(kp + (size_t)(kt + row) * DH_ + colc * 8);
            *(bf16x8*)(Vb + swzb(row, colc * 16)) =
                *(const bf16x8*)(vp + (size_t)row * S_ + kt + colc * 8);
        }
        __syncthreads();

        // ---- scores: S = Q K^T  (D-layout: row=lg*4+i, col=li) ----
        f32x4 sc[4];
        #pragma unroll
        for (int nt = 0; nt < 4; ++nt) sc[nt] = (f32x4){0.f, 0.f, 0.f, 0.f};
        #pragma unroll
        for (int kh = 0; kh < 2; ++kh) {
            #pragma unroll
            for (int nt = 0; nt < 4; ++nt) {
                bf16x8 kf = *(const bf16x8*)(Kb + swzb(nt * 16 + li, kh * 64 + lg * 16));
                sc[nt] = __builtin_amdgcn_mfma_f32_16x16x32_bf16(qf[kh], kf, sc[nt], 0, 0, 0);
            }
        }
        // additive mask
        #pragma unroll
        for (int nt = 0; nt < 4; ++nt) {
            float mv = mlds[kt + nt * 16 + li];
            #pragma unroll
            for (int i = 0; i < 4; ++i) sc[nt][i] += mv;
        }
        // ---- online softmax (per row i; reduce over li across 16-lane group) ----
        float pm[4];
        #pragma unroll
        for (int i = 0; i < 4; ++i) {
            pm[i] = fmaxf(fmaxf(sc[0][i], sc[1][i]), fmaxf(sc[2][i], sc[3][i]));
            pm[i] = fmaxf(pm[i], __shfl_xor(pm[i], 1));
            pm[i] = fmaxf(pm[i], __shfl_xor(pm[i], 2));
            pm[i] = fmaxf(pm[i], __shfl_xor(pm[i], 4));
            pm[i] = fmaxf(pm[i], __shfl_xor(pm[i], 8));
        }
        float alpha[4];
        #pragma unroll
        for (int i = 0; i < 4; ++i) {
            float mnew = fmaxf(mrow[i], pm[i]);
            alpha[i] = __expf(mrow[i] - mnew);
            mrow[i] = mnew;
        }
        float ls[4] = {0.f, 0.f, 0.f, 0.f};
        #pragma unroll
        for (int nt = 0; nt < 4; ++nt)
            #pragma unroll
            for (int i = 0; i < 4; ++i) {
                sc[nt][i] = __expf(sc[nt][i] - mrow[i]);
                ls[i] += sc[nt][i];
            }
        #pragma unroll
        for (int i = 0; i < 4; ++i) {
            ls[i] += __shfl_xor(ls[i], 1);
            ls[i] += __shfl_xor(ls[i], 2);
            ls[i] += __shfl_xor(ls[i], 4);
            ls[i] += __shfl_xor(ls[i], 8);
            lsum[i] = lsum[i] * alpha[i] + ls[i];
        }
        #pragma unroll
        for (int dt = 0; dt < 4; ++dt)
            #pragma unroll
            for (int i = 0; i < 4; ++i) o[dt][i] *= alpha[i];

        // ---- P -> LDS (bf16) ----
        #pragma unroll
        for (int nt = 0; nt < 4; ++nt)
            #pragma unroll
            for (int i = 0; i < 4; ++i)
                *(__hip_bfloat16*)(Pb + swzb(w * 16 + lg * 4 + i, (nt * 16 + li) * 2)) =
                    __float2bfloat16(sc[nt][i]);
        __syncthreads();

        // ---- PV: O += P V ----
        #pragma unroll
        for (int kh = 0; kh < 2; ++kh) {
            bf16x8 pf = *(const bf16x8*)(Pb + swzb(w * 16 + li, kh * 64 + lg * 16));
            #pragma unroll
            for (int dt = 0; dt < 4; ++dt) {
                bf16x8 vf = *(const bf16x8*)(Vb + swzb(dt * 16 + li, kh * 64 + lg * 16));
                o[dt] = __builtin_amdgcn_mfma_f32_16x16x32_bf16(pf, vf, o[dt], 0, 0, 0);
            }
        }
        __syncthreads();
    }

    // ---- epilogue: ctx[b][s][h*64+dh] = o / l ----
    float inv[4];
    #pragma unroll
    for (int i = 0; i < 4; ++i) inv[i] = 1.f / lsum[i];
    #pragma unroll
    for (int dt = 0; dt < 4; ++dt)
        #pragma unroll
        for (int i = 0; i < 4; ++i) {
            int s = q0 + w * 16 + lg * 4 + i;
            ctx[((size_t)bb * S_ + s) * D_ + hh * DH_ + dt * 16 + li] =
                __float2bfloat16(o[dt][i] * inv[i]);
        }
}

// ---------------- launch ----------------
extern "C" void kernel_launch(void* const* d_in, const int* in_sizes, int n_in,
                              void* d_out, int out_size, void* d_ws, size_t ws_size,
                              hipStream_t stream) {
    const float* query = (const float*)d_in[0];
    const float* key_  = (const float*)d_in[1];
    const float* value = (const float*)d_in[2];
    const float* mask  = (const float*)d_in[3];
    const float* Wq = (const float*)d_in[4];
    const float* bq = (const float*)d_in[5];
    const float* Wk = (const float*)d_in[6];
    const float* bk = (const float*)d_in[7];
    const float* Wv = (const float*)d_in[8];
    const float* bv = (const float*)d_in[9];
    const float* Wo = (const float*)d_in[10];
    const float* bo = (const float*)d_in[11];
    float* out = (float*)d_out;

    const size_t WSZ = (size_t)D_ * D_;             // 1M elems
    const size_t ASZ = (size_t)B_ * H_ * S_ * DH_;  // 8.4M elems
    __hip_bfloat16* wt  = (__hip_bfloat16*)d_ws;
    __hip_bfloat16* WtQ = wt;
    __hip_bfloat16* WtK = wt + WSZ;
    __hip_bfloat16* WtV = wt + 2 * WSZ;
    __hip_bfloat16* WtO = wt + 3 * WSZ;
    __hip_bfloat16* qws = wt + 4 * WSZ;
    __hip_bfloat16* kws = qws + ASZ;
    __hip_bfloat16* vtws = kws + ASZ;
    __hip_bfloat16* cws  = vtws + ASZ;

    dim3 tb(32, 8);
    dim3 tg(D_ / 32, D_ / 32);
    wtrans<<<tg, tb, 0, stream>>>(Wq, WtQ);
    wtrans<<<tg, tb, 0, stream>>>(Wk, WtK);
    wtrans<<<tg, tb, 0, stream>>>(Wv, WtV);
    wtrans<<<tg, tb, 0, stream>>>(Wo, WtO);

    dim3 gg(D_ / 128, M_ / 128);   // (8, 64)
    gemm_mfma<0><<<gg, 256, 0, stream>>>(query, WtQ, bq, qws, 0.125f);
    gemm_mfma<0><<<gg, 256, 0, stream>>>(key_,  WtK, bk, kws, 1.0f);
    gemm_mfma<2><<<gg, 256, 0, stream>>>(value, WtV, bv, vtws, 1.0f);

    attn_mfma<<<dim3(S_ / 64, B_ * H_), 256, 0, stream>>>(qws, kws, vtws, mask, cws);

    gemm_mfma<3><<<gg, 256, 0, stream>>>(cws, WtO, bo, out, 1.0f);
}

// Round 3
// 238.608 us; speedup vs baseline: 14.5127x; 1.6888x over previous
//
#include <hip/hip_runtime.h>
#include <hip/hip_bf16.h>

#define B_  4
#define S_  2048
#define D_  1024
#define H_  16
#define DH_ 64
#define M_  (B_*S_)   // 8192

typedef __attribute__((ext_vector_type(8)))  short    bf16x8;
typedef __attribute__((ext_vector_type(4)))  float    f32x4;
typedef __attribute__((ext_vector_type(16))) float    f32x16;
typedef __attribute__((ext_vector_type(2)))  unsigned u32x2;

#define LOG2E 1.4426950408889634f

// async global->LDS, 16B per lane (dest must be wave-uniform base + lane*16)
__device__ __forceinline__ void g2l16(const void* g, void* l) {
    __builtin_amdgcn_global_load_lds(
        (const __attribute__((address_space(1))) unsigned*)g,
        (__attribute__((address_space(3))) unsigned*)l, 16, 0, 0);
}

// ---------------- fp32 -> bf16 convert (3 tensors in one launch) ----------------
__global__ __launch_bounds__(256) void cvt_bf16_3(
    const float* __restrict__ x0, const float* __restrict__ x1, const float* __restrict__ x2,
    __hip_bfloat16* __restrict__ y0, __hip_bfloat16* __restrict__ y1, __hip_bfloat16* __restrict__ y2)
{
    const float* x = blockIdx.y == 0 ? x0 : (blockIdx.y == 1 ? x1 : x2);
    __hip_bfloat16* y = blockIdx.y == 0 ? y0 : (blockIdx.y == 1 ? y1 : y2);
    size_t i = ((size_t)blockIdx.x * 256 + threadIdx.x) * 8;
    float4 a = *(const float4*)(x + i);
    float4 b = *(const float4*)(x + i + 4);
    __hip_bfloat16 h[8];
    h[0] = __float2bfloat16(a.x); h[1] = __float2bfloat16(a.y);
    h[2] = __float2bfloat16(a.z); h[3] = __float2bfloat16(a.w);
    h[4] = __float2bfloat16(b.x); h[5] = __float2bfloat16(b.y);
    h[6] = __float2bfloat16(b.z); h[7] = __float2bfloat16(b.w);
    *(bf16x8*)(y + i) = *(const bf16x8*)h;
}

// ---------------- weight transpose + bf16: Wt[n][k] = bf16(W[k][n]), 4 in one ----------------
__global__ __launch_bounds__(256) void wtrans4(
    const float* __restrict__ W0, const float* __restrict__ W1,
    const float* __restrict__ W2, const float* __restrict__ W3,
    __hip_bfloat16* __restrict__ T0, __hip_bfloat16* __restrict__ T1,
    __hip_bfloat16* __restrict__ T2, __hip_bfloat16* __restrict__ T3)
{
    const float* W = blockIdx.z == 0 ? W0 : (blockIdx.z == 1 ? W1 : (blockIdx.z == 2 ? W2 : W3));
    __hip_bfloat16* Wt = blockIdx.z == 0 ? T0 : (blockIdx.z == 1 ? T1 : (blockIdx.z == 2 ? T2 : T3));
    __shared__ float t[32][33];
    const int bx = blockIdx.x * 32;   // n block
    const int by = blockIdx.y * 32;   // k block
    const int tx = threadIdx.x, ty = threadIdx.y;   // (32, 8)
    #pragma unroll
    for (int i = 0; i < 32; i += 8)
        t[ty + i][tx] = W[(size_t)(by + ty + i) * D_ + bx + tx];
    __syncthreads();
    #pragma unroll
    for (int i = 0; i < 32; i += 8)
        Wt[(size_t)(bx + ty + i) * D_ + by + tx] = __float2bfloat16(t[tx][ty + i]);
}

// ---------------- MFMA GEMM (m97 structure): Y = (X @ W + bias) * scale ----------------
// X: (8192,1024) bf16; Wt: (1024 n,1024 k) bf16.
// OUT 0: bf16 flat (M,N) | OUT 1: bf16 (B,H,DH,S) transposed | OUT 2: f32 flat
template<int OUT>
__global__ __launch_bounds__(256, 3) void gemm_bf16(
    const __hip_bfloat16* __restrict__ X, const __hip_bfloat16* __restrict__ Wt,
    const float* __restrict__ bias, void* __restrict__ Yv, float scale)
{
    __shared__ char Ab[16384];   // 128 rows x 64 bf16, linear 128B rows
    __shared__ char Bb[16384];

    const int tid = threadIdx.x;
    const int m0 = blockIdx.y * 128, n0 = blockIdx.x * 128;
    const int w = tid >> 6, l = tid & 63;
    const int wm = w >> 1, wn = w & 1;
    const int li = l & 15, lg = l >> 4;

    f32x4 acc[4][4];
    #pragma unroll
    for (int a = 0; a < 4; ++a)
        #pragma unroll
        for (int b = 0; b < 4; ++b)
            acc[a][b] = (f32x4){0.f, 0.f, 0.f, 0.f};

    for (int k0 = 0; k0 < D_; k0 += 64) {
        #pragma unroll
        for (int p = 0; p < 4; ++p) {
            int sl = p * 256 + tid;            // 0..1023 slots of 16B
            int row = sl >> 3, s = sl & 7;
            g2l16(X  + (size_t)(m0 + row) * D_ + k0 + s * 8, Ab + sl * 16);
            g2l16(Wt + (size_t)(n0 + row) * D_ + k0 + s * 8, Bb + sl * 16);
        }
        asm volatile("s_waitcnt vmcnt(0)");
        __syncthreads();

        #pragma unroll
        for (int kh = 0; kh < 2; ++kh) {
            bf16x8 af[4], bfr[4];
            #pragma unroll
            for (int mt = 0; mt < 4; ++mt)
                af[mt] = *(const bf16x8*)(Ab + (wm * 64 + mt * 16 + li) * 128 + kh * 64 + lg * 16);
            #pragma unroll
            for (int nt = 0; nt < 4; ++nt)
                bfr[nt] = *(const bf16x8*)(Bb + (wn * 64 + nt * 16 + li) * 128 + kh * 64 + lg * 16);
            #pragma unroll
            for (int mt = 0; mt < 4; ++mt)
                #pragma unroll
                for (int nt = 0; nt < 4; ++nt)
                    acc[mt][nt] = __builtin_amdgcn_mfma_f32_16x16x32_bf16(
                        af[mt], bfr[nt], acc[mt][nt], 0, 0, 0);
        }
        __syncthreads();
    }

    #pragma unroll
    for (int mt = 0; mt < 4; ++mt) {
        #pragma unroll
        for (int nt = 0; nt < 4; ++nt) {
            int col = n0 + wn * 64 + nt * 16 + li;
            float bv = bias[col];
            #pragma unroll
            for (int i = 0; i < 4; ++i) {
                int row = m0 + wm * 64 + mt * 16 + lg * 4 + i;
                float v = (acc[mt][nt][i] + bv) * scale;
                if (OUT == 0) {
                    ((__hip_bfloat16*)Yv)[(size_t)row * D_ + col] = __float2bfloat16(v);
                } else if (OUT == 1) {
                    int b = row >> 11, s = row & (S_ - 1);
                    int h = col >> 6,  dh = col & 63;
                    ((__hip_bfloat16*)Yv)[((((size_t)b * H_ + h) * DH_ + dh) << 11) + s] =
                        __float2bfloat16(v);
                } else {
                    ((float*)Yv)[(size_t)row * D_ + col] = v;
                }
            }
        }
    }
}

// ---------------- MFMA flash attention (swapped QK^T, in-register softmax) ----------------
// q,k: flat (M,D) bf16 (q pre-scaled by 0.125*log2e); vt: (B,H,DH,S) bf16;
// mask: (B,S) f32; ctx: (B,S,D) bf16.
__global__ __launch_bounds__(512, 4) void attn_mfma(
    const __hip_bfloat16* __restrict__ q, const __hip_bfloat16* __restrict__ k,
    const __hip_bfloat16* __restrict__ vt, const float* __restrict__ mask,
    __hip_bfloat16* __restrict__ ctx)
{
    __shared__ char Kb[2][8192];   // [kv 64][dh 64] bf16, slot-swizzled
    __shared__ char Vb[2][8192];   // [d 64][kv 64] bf16, slot-swizzled
    __shared__ float mlds[S_];     // mask * log2e

    const int tid = threadIdx.x;
    const int w = tid >> 6, l = tid & 63;
    const int q31 = l & 31, hi = l >> 5;
    const int bh = blockIdx.y, bb = bh >> 4, hh = bh & 15;
    const int q0 = blockIdx.x * 256;

    const __hip_bfloat16* kbase = k  + (size_t)bb * S_ * D_ + hh * 64;
    const __hip_bfloat16* vbase = vt + (size_t)bh * (DH_ * S_);

    // mask -> LDS (scaled to log2 domain)
    for (int i = tid; i < S_ / 4; i += 512) {
        float4 mv = ((const float4*)(mask + (size_t)bb * S_))[i];
        mv.x *= LOG2E; mv.y *= LOG2E; mv.z *= LOG2E; mv.w *= LOG2E;
        ((float4*)mlds)[i] = mv;
    }

    // Q fragments: wave's 32 q-rows; B-operand layout (col=lane&31, k=hi*8+j)
    const int qrow = q0 + w * 32 + q31;
    const __hip_bfloat16* qp = q + (size_t)(bb * S_ + qrow) * D_ + hh * 64;
    bf16x8 qf[4];
    #pragma unroll
    for (int mf = 0; mf < 4; ++mf)
        qf[mf] = *(const bf16x8*)(qp + mf * 16 + hi * 8);

    f32x16 ot0, ot1;   // O^T accumulators (d-tiles 0,1)
    #pragma unroll
    for (int r = 0; r < 16; ++r) { ot0[r] = 0.f; ot1[r] = 0.f; }
    float mrun = -1e30f, lsum = 0.f;

    // stage tile 0 (inverse-swizzled source, linear LDS dest)
    {
        int sl = tid, row = sl >> 3, s = sl & 7, sw = s ^ (row & 7);
        g2l16(kbase + (size_t)row * D_ + sw * 8, Kb[0] + sl * 16);
        g2l16(vbase + (size_t)row * S_ + sw * 8, Vb[0] + sl * 16);
    }
    asm volatile("s_waitcnt vmcnt(0)");
    __syncthreads();

    int cur = 0;
    for (int kt = 0; kt < S_; kt += 64) {
        if (kt + 64 < S_) {   // stage next tile (async, overlaps compute)
            int sl = tid, row = sl >> 3, s = sl & 7, sw = s ^ (row & 7);
            g2l16(kbase + (size_t)(kt + 64 + row) * D_ + sw * 8, Kb[cur ^ 1] + sl * 16);
            g2l16(vbase + (size_t)row * S_ + (kt + 64) + sw * 8, Vb[cur ^ 1] + sl * 16);
        }

        #pragma unroll
        for (int ks = 0; ks < 2; ++ks) {
            // ---- init acc with mask (log2 domain); Sc^T row kv=(r&3)+8*(r>>2)+4*hi ----
            f32x16 sc;
            #pragma unroll
            for (int g = 0; g < 4; ++g) {
                f32x4 mq = *(const f32x4*)(mlds + kt + ks * 32 + g * 8 + hi * 4);
                sc[g * 4 + 0] = mq[0]; sc[g * 4 + 1] = mq[1];
                sc[g * 4 + 2] = mq[2]; sc[g * 4 + 3] = mq[3];
            }
            // ---- Sc^T = K Q^T (swapped): lane owns q-col = lane&31 ----
            const int arow = ks * 32 + q31;
            #pragma unroll
            for (int mf = 0; mf < 4; ++mf) {
                int slot = (mf * 2 + hi) ^ (arow & 7);
                bf16x8 kf = *(const bf16x8*)(Kb[cur] + arow * 128 + slot * 16);
                sc = __builtin_amdgcn_mfma_f32_32x32x16_bf16(kf, qf[mf], sc, 0, 0, 0);
            }
            // ---- online softmax, in-register (defer-max THR=8) ----
            float a0 = fmaxf(sc[0], sc[1]),   a1 = fmaxf(sc[2], sc[3]);
            float a2 = fmaxf(sc[4], sc[5]),   a3 = fmaxf(sc[6], sc[7]);
            float a4 = fmaxf(sc[8], sc[9]),   a5 = fmaxf(sc[10], sc[11]);
            float a6 = fmaxf(sc[12], sc[13]), a7 = fmaxf(sc[14], sc[15]);
            float mt = fmaxf(fmaxf(fmaxf(a0, a1), fmaxf(a2, a3)),
                             fmaxf(fmaxf(a4, a5), fmaxf(a6, a7)));
            if (!__all(mt <= mrun + 8.0f)) {
                float mo = fmaxf(mt, __shfl_xor(mt, 32));
                float mnew = fmaxf(mrun, mo);
                float al = __builtin_amdgcn_exp2f(mrun - mnew);
                lsum *= al;
                #pragma unroll
                for (int r = 0; r < 16; ++r) { ot0[r] *= al; ot1[r] *= al; }
                mrun = mnew;
            }
            float ps[4] = {0.f, 0.f, 0.f, 0.f};
            #pragma unroll
            for (int r = 0; r < 16; ++r) {
                float e = __builtin_amdgcn_exp2f(sc[r] - mrun);
                sc[r] = e;
                ps[r & 3] += e;
            }
            lsum += (ps[0] + ps[1]) + (ps[2] + ps[3]);

            // ---- P^T f32 -> packed bf16 words ----
            unsigned pw[8];
            #pragma unroll
            for (int m = 0; m < 8; ++m) {
                float lo = sc[2 * m], hp = sc[2 * m + 1];
                unsigned r_;
                asm("v_cvt_pk_bf16_f32 %0, %1, %2" : "=v"(r_) : "v"(lo), "v"(hp));
                pw[m] = r_;
            }
            // ---- redistribute across hi-halves: one swap fills two frag words ----
            u32x2 s02 = __builtin_amdgcn_permlane32_swap(pw[0], pw[2], false, false);
            u32x2 s13 = __builtin_amdgcn_permlane32_swap(pw[1], pw[3], false, false);
            u32x2 s46 = __builtin_amdgcn_permlane32_swap(pw[4], pw[6], false, false);
            u32x2 s57 = __builtin_amdgcn_permlane32_swap(pw[5], pw[7], false, false);
            union { unsigned u[4]; bf16x8 v; } pf0, pf1;
            pf0.u[0] = s02[0]; pf0.u[1] = s13[0]; pf0.u[2] = s02[1]; pf0.u[3] = s13[1];
            pf1.u[0] = s46[0]; pf1.u[1] = s57[0]; pf1.u[2] = s46[1]; pf1.u[3] = s57[1];

            // ---- O^T += V^T P^T ----
            #pragma unroll
            for (int kh = 0; kh < 2; ++kh) {
                bf16x8 pf = kh ? pf1.v : pf0.v;
                #pragma unroll
                for (int dt = 0; dt < 2; ++dt) {
                    int row = dt * 32 + q31;
                    int slot = (ks * 4 + kh * 2 + hi) ^ (row & 7);
                    bf16x8 vf = *(const bf16x8*)(Vb[cur] + row * 128 + slot * 16);
                    if (dt == 0)
                        ot0 = __builtin_amdgcn_mfma_f32_32x32x16_bf16(vf, pf, ot0, 0, 0, 0);
                    else
                        ot1 = __builtin_amdgcn_mfma_f32_32x32x16_bf16(vf, pf, ot1, 0, 0, 0);
                }
            }
        }
        asm volatile("s_waitcnt vmcnt(0)");
        __syncthreads();   // next buffer staged & everyone done reading cur
        cur ^= 1;
    }

    // ---- epilogue: ctx[b][s][h*64+d] = O^T[d][q] / l ----
    float lt = lsum + __shfl_xor(lsum, 32);
    float inv = 1.0f / lt;
    __hip_bfloat16* cp = ctx + (size_t)(bb * S_ + qrow) * D_ + hh * 64;
    #pragma unroll
    for (int dt = 0; dt < 2; ++dt) {
        #pragma unroll
        for (int g = 0; g < 4; ++g) {
            float v0 = (dt ? ot1[g * 4 + 0] : ot0[g * 4 + 0]) * inv;
            float v1 = (dt ? ot1[g * 4 + 1] : ot0[g * 4 + 1]) * inv;
            float v2 = (dt ? ot1[g * 4 + 2] : ot0[g * 4 + 2]) * inv;
            float v3 = (dt ? ot1[g * 4 + 3] : ot0[g * 4 + 3]) * inv;
            unsigned w0, w1;
            asm("v_cvt_pk_bf16_f32 %0, %1, %2" : "=v"(w0) : "v"(v0), "v"(v1));
            asm("v_cvt_pk_bf16_f32 %0, %1, %2" : "=v"(w1) : "v"(v2), "v"(v3));
            u32x2 st; st[0] = w0; st[1] = w1;
            *(u32x2*)(cp + dt * 32 + g * 8 + hi * 4) = st;
        }
    }
}

// ---------------- launch ----------------
extern "C" void kernel_launch(void* const* d_in, const int* in_sizes, int n_in,
                              void* d_out, int out_size, void* d_ws, size_t ws_size,
                              hipStream_t stream) {
    const float* query = (const float*)d_in[0];
    const float* key_  = (const float*)d_in[1];
    const float* value = (const float*)d_in[2];
    const float* mask  = (const float*)d_in[3];
    const float* Wq = (const float*)d_in[4];
    const float* bq = (const float*)d_in[5];
    const float* Wk = (const float*)d_in[6];
    const float* bk = (const float*)d_in[7];
    const float* Wv = (const float*)d_in[8];
    const float* bv = (const float*)d_in[9];
    const float* Wo = (const float*)d_in[10];
    const float* bo = (const float*)d_in[11];
    float* out = (float*)d_out;

    const size_t WSZ = (size_t)D_ * D_;   // 1M elems
    const size_t ASZ = (size_t)M_ * D_;   // 8.4M elems
    __hip_bfloat16* p   = (__hip_bfloat16*)d_ws;
    __hip_bfloat16* WtQ = p;            p += WSZ;
    __hip_bfloat16* WtK = p;            p += WSZ;
    __hip_bfloat16* WtV = p;            p += WSZ;
    __hip_bfloat16* WtO = p;            p += WSZ;
    __hip_bfloat16* Xq  = p;            p += ASZ;
    __hip_bfloat16* Xk  = p;            p += ASZ;
    __hip_bfloat16* Xv  = p;            p += ASZ;
    __hip_bfloat16* qb  = p;            p += ASZ;
    __hip_bfloat16* kb  = p;            p += ASZ;
    __hip_bfloat16* vtb = p;            p += ASZ;
    __hip_bfloat16* cb  = p;            p += ASZ;

    cvt_bf16_3<<<dim3(4096, 3), 256, 0, stream>>>(query, key_, value, Xq, Xk, Xv);
    wtrans4<<<dim3(32, 32, 4), dim3(32, 8), 0, stream>>>(Wq, Wk, Wv, Wo, WtQ, WtK, WtV, WtO);

    dim3 gg(D_ / 128, M_ / 128);   // (8, 64)
    gemm_bf16<0><<<gg, 256, 0, stream>>>(Xq, WtQ, bq, qb, 0.125f * LOG2E);  // q in log2 domain
    gemm_bf16<0><<<gg, 256, 0, stream>>>(Xk, WtK, bk, kb, 1.0f);
    gemm_bf16<1><<<gg, 256, 0, stream>>>(Xv, WtV, bv, vtb, 1.0f);

    attn_mfma<<<dim3(S_ / 256, B_ * H_), 512, 0, stream>>>(qb, kb, vtb, mask, cb);

    gemm_bf16<2><<<gg, 256, 0, stream>>>(cb, WtO, bo, out, 1.0f);
}